// Round 7
// baseline (248.755 us; speedup 1.0000x reference)
//
#include <hip/hip_runtime.h>
#include <math.h>

#define TMAXV 20.0f
#define L2E 1.4426950408889634f
#define LN2 0.6931471805599453f

typedef __fp16 h2 __attribute__((ext_vector_type(2)));

__device__ __forceinline__ float fexp2(float x){ return __builtin_amdgcn_exp2f(x); }
__device__ __forceinline__ float flog2(float x){ return __builtin_amdgcn_logf(x); }
__device__ __forceinline__ float frcp(float x){ return __builtin_amdgcn_rcpf(x); }
__device__ __forceinline__ float fsig(float x){ return frcp(1.0f + fexp2(-x * L2E)); }
__device__ __forceinline__ float ftanh_(float x){ return 1.0f - 2.0f * frcp(1.0f + fexp2(2.0f * x * L2E)); }
__device__ __forceinline__ h2 as_h2(int v){ return __builtin_bit_cast(h2, v); }

template <int CTRL>
__device__ __forceinline__ float dppmov(float x) {
    return __int_as_float(__builtin_amdgcn_update_dpp(0, __float_as_int(x), CTRL, 0xf, 0xf, false));
}
// wave64 sum -> uniform (validated round 2)
__device__ __forceinline__ float wsum(float x) {
    x += dppmov<0x111>(x);  // row_shr:1
    x += dppmov<0x112>(x);  // row_shr:2
    x += dppmov<0x114>(x);  // row_shr:4
    x += dppmov<0x118>(x);  // row_shr:8
    x += dppmov<0x142>(x);  // row_bcast:15
    x += dppmov<0x143>(x);  // row_bcast:31
    return __int_as_float(__builtin_amdgcn_readlane(__float_as_int(x), 63));
}
__device__ __forceinline__ float wsum_shfl(float v) {
    v += __shfl_xor(v, 1);  v += __shfl_xor(v, 2);  v += __shfl_xor(v, 4);
    v += __shfl_xor(v, 8);  v += __shfl_xor(v, 16); v += __shfl_xor(v, 32);
    return v;
}

// grid = 256 blocks x 256 threads, 1 block/CU.
//  blocks [0,64):    LSTM rollout, 4 waves. Wave w owns gate rows [64w,64w+64);
//                    lane = 1 full row as 32 f16-pair VGPRs (small enough to be
//                    truly register-resident: rounds 4-6 showed >=128-VGPR weight
//                    arrays ALWAYS spill to scratch; with 1 wave/CU that exposed
//                    ~2400 cyc/step of uncovered L1 latency). hx kept as f16 in
//                    one shared LDS array (broadcast b128 reads, half of round-2
//                    LDS-pipe traffic). One barrier/step (act exchange); cell
//                    update + sigma computed redundantly in all 4 waves.
//  blocks [64,192):  expert-expert MMD term (input-only, runs concurrently).
//  blocks [192,256): spin on done==64, then ll + le over COMPACTED learner pts.
__global__ __launch_bounds__(256, 1) void fused(
    const float* __restrict__ up,    // [64,128] uniform pool
    const float* __restrict__ te,    // [64,128] expert times
    const float* __restrict__ Wih,   // [256]
    const float* __restrict__ Whh,   // [256,64]
    const float* __restrict__ bih,   // [256]
    const float* __restrict__ bhh,   // [256]
    const float* __restrict__ Vw,    // [64]
    const float* __restrict__ Vb,    // [1]
    unsigned int* __restrict__ hdr,  // ws: [0]=compacted count, [1]=done blocks
    float* __restrict__ comp,        // ws+16: compacted learner times (<=8192)
    float* __restrict__ out)         // [1] loss
{
    __shared__ float2 qbuf[2048];                // ee branch
    __shared__ float act_s[2][256];              // gate activations, double-buffered
    __shared__ __align__(16) int hxp[32];        // hx as 64 f16 (32 packed dwords)
    __shared__ float lu_s[128];                  // -ln(u) per step

    const int bid = blockIdx.x;
    const int tid = threadIdx.x;

    if (bid < 64) {
        const int l  = tid & 63;
        const int wv = tid >> 6;

        // stage -ln(u) and zero hx
        if (tid < 128) lu_s[tid] = -flog2(up[bid * 128 + tid]) * LN2;
        if (tid < 32) hxp[tid] = 0;

        // this lane's full gate row, f16-packed: 32 VGPRs
        h2 wreg[32];
        const float4* rp = (const float4*)(Whh + tid * 64);
        #pragma unroll
        for (int j = 0; j < 16; ++j) {
            float4 q = rp[j];
            wreg[2 * j]     = __builtin_amdgcn_cvt_pkrtz(q.x, q.y);
            wreg[2 * j + 1] = __builtin_amdgcn_cvt_pkrtz(q.z, q.w);
        }
        const float bias = bih[tid] + bhh[tid];
        const float wih  = Wih[tid];
        const float vwl  = Vw[l];
        const float vb   = Vb[0];
        __syncthreads();

        // step 0: hx=0 -> sigma = elu(vb)+1 (elu(x)+1 == exp(x) for x<=0)
        float sg0 = (vb > 0.0f) ? (vb + 1.0f) : fexp2(vb * L2E);
        float cum = lu_s[0] * frcp(sg0);
        float h0 = (l == 0) ? cum : 1e30f;   // t[s] for s = l
        float h1 = 1e30f;                    // t[s] for s = 64+l
        float cx = 0.0f, hx = 0.0f;

        for (int s = 0; s < 127; ++s) {
            // matvec: row(tid) dot hx; hx broadcast from LDS as 8x b128 (f16)
            const int4* hx4 = (const int4*)hxp;
            float d0 = 0.f, d1 = 0.f, d2 = 0.f, d3 = 0.f;
            #pragma unroll
            for (int k = 0; k < 8; ++k) {
                int4 hq = hx4[k];
                d0 = __builtin_amdgcn_fdot2(wreg[4 * k + 0], as_h2(hq.x), d0, false);
                d1 = __builtin_amdgcn_fdot2(wreg[4 * k + 1], as_h2(hq.y), d1, false);
                d2 = __builtin_amdgcn_fdot2(wreg[4 * k + 2], as_h2(hq.z), d2, false);
                d3 = __builtin_amdgcn_fdot2(wreg[4 * k + 3], as_h2(hq.w), d3, false);
            }
            float g = (d0 + d1) + (d2 + d3) + fmaf(cum, wih, bias);
            float a = (wv == 2) ? ftanh_(g) : fsig(g);
            act_s[s & 1][tid] = a;
            __syncthreads();   // the ONLY barrier per step

            // redundant cell update in all 4 waves (bit-identical)
            float ig = act_s[s & 1][l];
            float fg = act_s[s & 1][64 + l];
            float gg = act_s[s & 1][128 + l];
            float og = act_s[s & 1][192 + l];
            cx = fg * cx + ig * gg;
            hx = og * ftanh_(cx);

            // pack (hx[2k],hx[2k+1]) and write; 4 waves write identical values
            // (benign). Safe single-buffer: hx(s) reads happen before this
            // step's barrier, hx(s+1) writes after it.
            float hxn = dppmov<0xB1>(hx);    // quad_perm [1,0,3,2]: neighbor
            int pk = __builtin_bit_cast(int, __builtin_amdgcn_cvt_pkrtz(hx, hxn));
            if ((l & 1) == 0) hxp[l >> 1] = pk;

            float tot = wsum(hx * vwl);
            float xx  = tot + vb;
            float sg  = (xx > 0.0f) ? (xx + 1.0f) : fexp2(xx * L2E);
            int idx = s + 1;
            cum += lu_s[idx] * frcp(sg);
            h0 = (l == idx)      ? cum : h0;
            h1 = (l == idx - 64) ? cum : h1;
        }

        // compacted append (wave 0 only): times monotone -> actives are a prefix
        if (tid < 64) {
            unsigned long long b0 = __ballot(h0 < TMAXV);
            unsigned long long b1 = __ballot(h1 < TMAXV);
            int n0 = __popcll(b0), n1 = __popcll(b1);
            int base = 0;
            if (l == 0) base = (int)atomicAdd(&hdr[0], (unsigned)(n0 + n1));
            base = __shfl(base, 0);
            if (h0 < TMAXV) comp[base + l] = h0;
            if (h1 < TMAXV) comp[base + 64 + l] = h1;   // only when n0==64
            __threadfence();
            if (l == 0) atomicAdd(&hdr[1], 1u);
        }
    } else if (bid < 192) {
        // ---------------- expert-expert MMD term ----------------
        const int eb = bid - 64;         // 0..127
        const int pc = eb & 31;
        const int qs = eb >> 5;
        const int p = pc * 256 + tid;
        const float tp = te[p];
        const float mp = (tp < TMAXV && tp > 0.0f) ? 1.0f : 0.0f;
        const int q0 = qs * 2048;
        for (int i = tid; i < 2048; i += 256) {
            float tq = te[q0 + i];
            float mq = (tq < TMAXV && tq > 0.0f) ? 1.0f : 0.0f;
            qbuf[i] = make_float2(tq, mq);
        }
        __syncthreads();
        float acc = 0.0f;
        #pragma unroll 4
        for (int i = 0; i < 2048; ++i) {
            float2 q = qbuf[i];
            float d = tp - q.x;
            acc = fmaf(q.y, fexp2(d * d * (-L2E)), acc);
        }
        acc *= mp;
        acc = wsum_shfl(acc);
        if ((tid & 63) == 0) atomicAdd(out, acc);
    } else {
        // ---------------- ll + le on compacted learner points ----------------
        if (tid == 0) {
            while (atomicAdd(&hdr[1], 0u) < 64u) __builtin_amdgcn_s_sleep(16);
        }
        __syncthreads();
        __threadfence();   // acquire before reading comp
        const int n = (int)*(volatile unsigned int*)&hdr[0];
        const int gid = (bid - 192) * 256 + tid;   // 0..16383
        const int pg = gid >> 5;                   // p-group (32 lanes each)
        const int sl = gid & 31;
        float acc = 0.0f;
        for (int pi = pg; pi < n; pi += 512) {
            float tp = comp[pi];                   // active by construction
            float all_ = 0.0f, ale = 0.0f;
            for (int j = sl; j < 8192; j += 32) {
                float t = te[j];
                float m = (t < TMAXV && t > 0.0f) ? 1.0f : 0.0f;
                float d = tp - t;
                ale = fmaf(m, fexp2(d * d * (-L2E)), ale);
            }
            for (int j = sl; j < n; j += 32) {
                float d = tp - comp[j];
                all_ += fexp2(d * d * (-L2E));
            }
            acc += all_ - 2.0f * ale;
        }
        acc = wsum_shfl(acc);
        if ((tid & 63) == 0) atomicAdd(out, acc);
    }
}

extern "C" void kernel_launch(void* const* d_in, const int* in_sizes, int n_in,
                              void* d_out, int out_size, void* d_ws, size_t ws_size,
                              hipStream_t stream) {
    const float* up  = (const float*)d_in[0];
    const float* te  = (const float*)d_in[1];
    const float* Wih = (const float*)d_in[2];
    const float* Whh = (const float*)d_in[3];
    const float* bih = (const float*)d_in[4];
    const float* bhh = (const float*)d_in[5];
    const float* Vw  = (const float*)d_in[6];
    const float* Vb  = (const float*)d_in[7];
    unsigned int* hdr = (unsigned int*)d_ws;
    float* comp = (float*)d_ws + 4;
    float* out = (float*)d_out;

    (void)hipMemsetAsync(d_ws, 0, 16, stream);
    (void)hipMemsetAsync(d_out, 0, 4, stream);
    hipLaunchKernelGGL(fused, dim3(256), dim3(256), 0, stream,
                       up, te, Wih, Whh, bih, bhh, Vw, Vb, hdr, comp, out);
}